// Round 6
// baseline (818.067 us; speedup 1.0000x reference)
//
#include <hip/hip_runtime.h>
#include <stdint.h>

// CrossAttn: B=2, Nr=Np=8192, C=256, K=8. ALL I/O float32 (per reference).
// Evidence trail: bf16-decode produced NaN d2 -> unfilled KNN heaps -> wild
// gather faults (R2-R4) and NaN output (R5). f32 decode fixes both.
// Folds:
//  - output ref-half rows are exactly zero.
//  - linear chain folds: A = Wout@Wo@Wv [512,256] (bf16), bbig = Wout@(Wo@bv+bo).
//  - d2 matches np f32: rounded products, sequential adds, (d2,idx)-lex ties.
// Scratch: NO d_ws. All scratch inside d_out's batch-0 ref half [0,16MB):
//   g bf16 8MB -> [0,8M); part 2MB -> [8M,10M); ref4 256K -> [10M,..);
//   idx 512K -> [10.25M,..); Aw 256K -> [10.75M,..); bbig 2K -> [11M,..)
// k_gemm writes pred halves [16M,32M)+[48M,64M); k_zero zeroes ref halves LAST.

#define NRr 8192
#define NPp 8192
#define NC  256
#define NK  8

typedef short bf16x8 __attribute__((ext_vector_type(8)));
typedef float f32x4  __attribute__((ext_vector_type(4)));

__device__ __forceinline__ uint16_t f2bf(float f) {
  uint32_t u = __float_as_uint(f);
  return (uint16_t)((u + 0x7fffu + ((u >> 16) & 1u)) >> 16);
}

// ---------------- prep: ref coords + |r|^2 (literal np rounding) ------------
__global__ void k_prep(const float* __restrict__ xyz_ref, float4* __restrict__ ref4) {
  int i = blockIdx.x * 256 + threadIdx.x;      // 0 .. 2*NR-1
  if (i >= 2 * NRr) return;
  float x = xyz_ref[i*3+0];
  float y = xyz_ref[i*3+1];
  float z = xyz_ref[i*3+2];
  float n = __fadd_rn(__fadd_rn(__fmul_rn(x,x), __fmul_rn(y,y)), __fmul_rn(z,z));
  ref4[i] = make_float4(x, y, z, n);
}

// sorted-8 insert, strict < on d2 (scan order ascending idx => lex-stable)
__device__ __forceinline__ void insert8(float d2, int j, float (&dist)[8], int (&id)[8]) {
  if (d2 < dist[7]) {
    #pragma unroll
    for (int k = 7; k >= 1; --k) {
      bool sh = d2 < dist[k-1];
      bool pl = d2 < dist[k];
      float nd = sh ? dist[k-1] : (pl ? d2 : dist[k]);
      int   ni = sh ? id[k-1]   : (pl ? j  : id[k]);
      dist[k] = nd; id[k] = ni;
    }
    if (d2 < dist[0]) { dist[0] = d2; id[0] = j; }
  }
}

// ---------------- brute-force KNN, 2 ref-halves per point -------------------
#define KTILE 2048
__global__ __launch_bounds__(64) void k_knn(const float* __restrict__ xyz_pred,
                                            const float4* __restrict__ ref4,
                                            float2* __restrict__ part) {
  __shared__ __align__(16) float4 sref[KTILE];
  int blk  = blockIdx.x;            // 0..511
  int half = blk & 1;
  int P    = (blk >> 1) * 64 + threadIdx.x;   // global point 0..16383
  int b    = P >> 13;

  float px = xyz_pred[P*3+0];
  float py = xyz_pred[P*3+1];
  float pz = xyz_pred[P*3+2];
  float sp = __fadd_rn(__fadd_rn(__fmul_rn(px,px), __fmul_rn(py,py)), __fmul_rn(pz,pz));

  float dist[8]; int id[8];
  #pragma unroll
  for (int k = 0; k < 8; ++k) { dist[k] = 3.4e38f; id[k] = 0; }

  const float4* refbase = ref4 + (size_t)b * NRr;
  int rbase = half * 4096;

  for (int tt = 0; tt < 4096; tt += KTILE) {
    for (int j = threadIdx.x; j < KTILE; j += 64) sref[j] = refbase[rbase + tt + j];
    __syncthreads();
    for (int j = 0; j < KTILE; j += 2) {
      float4 r0 = sref[j];
      float4 r1 = sref[j+1];
      float d0, d1;
      {
        float m0 = __fmul_rn(px, r0.x), m1 = __fmul_rn(py, r0.y), m2 = __fmul_rn(pz, r0.z);
        float dot = __fadd_rn(__fadd_rn(m0, m1), m2);
        d0 = __fsub_rn(__fadd_rn(sp, r0.w), __fadd_rn(dot, dot));
      }
      {
        float m0 = __fmul_rn(px, r1.x), m1 = __fmul_rn(py, r1.y), m2 = __fmul_rn(pz, r1.z);
        float dot = __fadd_rn(__fadd_rn(m0, m1), m2);
        d1 = __fsub_rn(__fadd_rn(sp, r1.w), __fadd_rn(dot, dot));
      }
      if (d0 < dist[7] || d1 < dist[7]) {
        insert8(d0, rbase + tt + j,     dist, id);
        insert8(d1, rbase + tt + j + 1, dist, id);
      }
    }
    __syncthreads();
  }
  float2* pp = part + ((size_t)P * 2 + half) * 8;
  #pragma unroll
  for (int k = 0; k < 8; ++k)
    pp[k] = make_float2(dist[k], __int_as_float(id[k] & (NRr - 1)));
}

// lex (d2, idx) insert for the merge of the two halves
__device__ __forceinline__ void insert_lex(float d2, int j, float (&dist)[8], int (&id)[8]) {
  bool b7 = (d2 < dist[7]) || (d2 == dist[7] && j < id[7]);
  if (b7) {
    #pragma unroll
    for (int k = 7; k >= 1; --k) {
      bool sh = (d2 < dist[k-1]) || (d2 == dist[k-1] && j < id[k-1]);
      bool pl = (d2 < dist[k])   || (d2 == dist[k]   && j < id[k]);
      float nd = sh ? dist[k-1] : (pl ? d2 : dist[k]);
      int   ni = sh ? id[k-1]   : (pl ? j  : id[k]);
      dist[k] = nd; id[k] = ni;
    }
    bool p0 = (d2 < dist[0]) || (d2 == dist[0] && j < id[0]);
    if (p0) { dist[0] = d2; id[0] = j; }
  }
}

__global__ void k_merge(const float2* __restrict__ part, int* __restrict__ idx) {
  int P = blockIdx.x * 256 + threadIdx.x;   // 0..16383
  float dist[8]; int id[8];
  #pragma unroll
  for (int k = 0; k < 8; ++k) { dist[k] = 3.4e38f; id[k] = NRr - 1; }
  const float2* pp = part + (size_t)P * 16;
  for (int c = 0; c < 16; ++c) {
    float2 v = pp[c];
    insert_lex(v.x, __float_as_int(v.y) & (NRr - 1), dist, id);
  }
  #pragma unroll
  for (int k = 0; k < 8; ++k) idx[(size_t)P*8 + k] = id[k] & (NRr - 1);
}

// ---------------- fold Wout@Wo@Wv -> A [512,256] bf16, bbig f32 -------------
__global__ __launch_bounds__(256) void k_combine(const float* __restrict__ Wv,
    const float* __restrict__ bv, const float* __restrict__ Wo,
    const float* __restrict__ bo, const float* __restrict__ Wout,
    uint16_t* __restrict__ Aw, float* __restrict__ bbig) {
  __shared__ float M[256];
  __shared__ float red[256];
  int e = blockIdx.x;      // 0..511
  int t = threadIdx.x;     // 0..255
  float acc = 0.f;
  for (int d = 0; d < 256; ++d)
    acc = fmaf(Wout[(size_t)e*256 + d], Wo[(size_t)d*256 + t], acc);
  M[t] = acc;
  red[t] = fmaf(acc, bv[t], Wout[(size_t)e*256 + t] * bo[t]);
  __syncthreads();
  float a2 = 0.f;
  for (int c = 0; c < 256; ++c)
    a2 = fmaf(M[c], Wv[(size_t)c*256 + t], a2);
  Aw[(size_t)e*256 + t] = f2bf(a2);
  for (int s2 = 128; s2 > 0; s2 >>= 1) {
    if (t < s2) red[t] += red[t + s2];
    __syncthreads();
  }
  if (t == 0) bbig[e] = red[0];
}

// ---------------- attention: one wave per pred point ------------------------
__global__ __launch_bounds__(256) void k_attn(const float* __restrict__ feat_q,
    const float* __restrict__ feat_k, const float* __restrict__ feat_v,
    const int* __restrict__ idx, uint16_t* __restrict__ g) {
  int wave = threadIdx.x >> 6;
  int lane = threadIdx.x & 63;
  int P = blockIdx.x * 4 + wave;     // 0..16383
  int b = P >> 13;
  const int* ip = idx + (size_t)P * 8;
  int nb[8];
  #pragma unroll
  for (int k = 0; k < 8; ++k) nb[k] = ip[k] & (NRr - 1);

  float4 qv = *(const float4*)(feat_q + (size_t)P*NC + lane*4);
  const float* kb = feat_k + (size_t)b * NRr * NC;
  const float* vb = feat_v + (size_t)b * NRr * NC;

  float s[8];
  #pragma unroll
  for (int k = 0; k < 8; ++k) {
    float4 kv = *(const float4*)(kb + (size_t)nb[k]*NC + lane*4);
    float p = qv.x * kv.x;
    p = fmaf(qv.y, kv.y, p);
    p = fmaf(qv.z, kv.z, p);
    p = fmaf(qv.w, kv.w, p);
    s[k] = p;
  }
  #pragma unroll
  for (int k = 0; k < 8; ++k) {
    float v = s[k];
    #pragma unroll
    for (int m = 1; m < 64; m <<= 1) v += __shfl_xor(v, m, 64);
    s[k] = v * 0.0625f;   // / sqrt(256), exact
  }
  float mx = s[0];
  #pragma unroll
  for (int k = 1; k < 8; ++k) mx = fmaxf(mx, s[k]);
  float e[8], sum = 0.f;
  #pragma unroll
  for (int k = 0; k < 8; ++k) { e[k] = expf(s[k] - mx); sum += e[k]; }
  float inv = 1.0f / sum;

  float g0 = 0.f, g1 = 0.f, g2 = 0.f, g3 = 0.f;
  #pragma unroll
  for (int k = 0; k < 8; ++k) {
    float4 vv = *(const float4*)(vb + (size_t)nb[k]*NC + lane*4);
    float w = e[k] * inv;
    g0 = fmaf(w, vv.x, g0);
    g1 = fmaf(w, vv.y, g1);
    g2 = fmaf(w, vv.z, g2);
    g3 = fmaf(w, vv.w, g3);
  }
  uint32_t p0 = ((uint32_t)f2bf(g1) << 16) | f2bf(g0);
  uint32_t p1 = ((uint32_t)f2bf(g3) << 16) | f2bf(g2);
  *(uint2*)(g + (size_t)P*NC + lane*4) = make_uint2(p0, p1);
}

// ---------------- zero-fill ref halves of output (runs LAST) ----------------
__global__ void k_zero(float4* __restrict__ o) {
  int i = blockIdx.x * 256 + threadIdx.x;  // 0 .. 2097151
  int b = i >> 20;                         // region 0 or 1
  int r = i & 1048575;                     // 1M float4 per 16MB region
  o[(size_t)b * 2097152 + r] = make_float4(0.f, 0.f, 0.f, 0.f);
}

// ---------------- final GEMM: g[16384,256]bf16 @ A^T + bbig -> f32 ----------
__global__ __launch_bounds__(256) void k_gemm(const uint16_t* __restrict__ g,
    const uint16_t* __restrict__ Aw, const float* __restrict__ bbig,
    float* __restrict__ outp) {
  // LDS stride 136 (272B): 16B-aligned rows, 4-bank shift/row => conflict-free
  __shared__ __align__(16) uint16_t sA[64 * 136];
  __shared__ __align__(16) uint16_t sB[64 * 136];
  int t = threadIdx.x;
  int lane = t & 63, wave = t >> 6;
  int wm = (wave >> 1) * 32, wn = (wave & 1) * 32;
  int q = lane >> 4, rr = lane & 15;
  int bm = blockIdx.x;   // 0..255 (M tiles of 64)
  int bn = blockIdx.y;   // 0..7   (N tiles of 64)
  f32x4 zero = {0.f, 0.f, 0.f, 0.f};
  f32x4 acc[2][2] = {{zero, zero}, {zero, zero}};

  for (int ph = 0; ph < 2; ++ph) {      // K = 256 in two 128 phases
    #pragma unroll
    for (int i = 0; i < 4; ++i) {
      int cc  = t + i * 256;            // 0..1023 chunks of 8 bf16
      int row = cc >> 4;                // 16 chunks per row
      int col = (cc & 15) << 3;
      uint4 da = *(const uint4*)(g  + ((size_t)(bm*64 + row))*NC + ph*128 + col);
      *(uint4*)(&sA[row*136 + col]) = da;
      uint4 db = *(const uint4*)(Aw + ((size_t)(bn*64 + row))*NC + ph*128 + col);
      *(uint4*)(&sB[row*136 + col]) = db;
    }
    __syncthreads();
    #pragma unroll
    for (int kk = 0; kk < 4; ++kk) {
      int ko = kk*32 + q*8;
      bf16x8 a0 = *(const bf16x8*)(&sA[(wm      + rr)*136 + ko]);
      bf16x8 a1 = *(const bf16x8*)(&sA[(wm + 16 + rr)*136 + ko]);
      bf16x8 b0 = *(const bf16x8*)(&sB[(wn      + rr)*136 + ko]);
      bf16x8 b1 = *(const bf16x8*)(&sB[(wn + 16 + rr)*136 + ko]);
      acc[0][0] = __builtin_amdgcn_mfma_f32_16x16x32_bf16(a0, b0, acc[0][0], 0, 0, 0);
      acc[0][1] = __builtin_amdgcn_mfma_f32_16x16x32_bf16(a0, b1, acc[0][1], 0, 0, 0);
      acc[1][0] = __builtin_amdgcn_mfma_f32_16x16x32_bf16(a1, b0, acc[1][0], 0, 0, 0);
      acc[1][1] = __builtin_amdgcn_mfma_f32_16x16x32_bf16(a1, b1, acc[1][1], 0, 0, 0);
    }
    __syncthreads();
  }
  #pragma unroll
  for (int j = 0; j < 2; ++j) {
    int col = bn*64 + wn + j*16 + rr;
    float bias = bbig[col];
    #pragma unroll
    for (int i = 0; i < 2; ++i) {
      #pragma unroll
      for (int r = 0; r < 4; ++r) {
        int row = bm*64 + wm + i*16 + q*4 + r;   // C/D: col=lane&15, row=(lane>>4)*4+reg
        float v = acc[i][j][r] + bias;
        int bb = row >> 13, p = row & 8191;
        outp[((size_t)(bb*16384 + 8192 + p))*512 + col] = v;
      }
    }
  }
}

extern "C" void kernel_launch(void* const* d_in, const int* in_sizes, int n_in,
                              void* d_out, int out_size, void* d_ws, size_t ws_size,
                              hipStream_t stream) {
  const float* xyz_ref  = (const float*)d_in[0];
  const float* xyz_pred = (const float*)d_in[1];
  const float* feat_k   = (const float*)d_in[2];
  const float* feat_q   = (const float*)d_in[3];
  const float* feat_v   = (const float*)d_in[4];
  const float* Wv       = (const float*)d_in[5];
  const float* bv       = (const float*)d_in[6];
  const float* Wo       = (const float*)d_in[7];
  const float* bo       = (const float*)d_in[8];
  const float* Wout     = (const float*)d_in[9];
  float* outp = (float*)d_out;

  // ALL scratch inside d_out's batch-0 ref half [0, 16MB) (f32 output, 64MB):
  char* ob = (char*)d_out;
  uint16_t* g    = (uint16_t*)ob;                    // [0, 8M)    bf16 16384x256
  float2*   part = (float2*)(ob + 8388608);          // [8M, 10M)
  float4*   ref4 = (float4*)(ob + 10485760);         // [10M, 10.25M)
  int*      idx  = (int*)(ob + 10747904);            // [10.25M, 10.75M)
  uint16_t* Aw   = (uint16_t*)(ob + 11272192);       // [10.75M, 11M)
  float*    bbig = (float*)(ob + 11534336);          // [11M, +2K)

  k_prep   <<<64,   256, 0, stream>>>(xyz_ref, ref4);
  k_knn    <<<512,  64,  0, stream>>>(xyz_pred, ref4, part);
  k_merge  <<<64,   256, 0, stream>>>(part, idx);
  k_combine<<<512,  256, 0, stream>>>(Wv, bv, Wo, bo, Wout, Aw, bbig);
  k_attn   <<<4096, 256, 0, stream>>>(feat_q, feat_k, feat_v, idx, g);
  k_gemm   <<<dim3(256, 8), 256, 0, stream>>>(g, Aw, bbig, outp);
  k_zero   <<<8192, 256, 0, stream>>>((float4*)outp);
}

// Round 8
// 522.745 us; speedup vs baseline: 1.5649x; 1.5649x over previous
//
#include <hip/hip_runtime.h>
#include <stdint.h>

// CrossAttn: B=2, Nr=Np=8192, C=256, K=8. ALL I/O float32.
// R6 passed (absmax 0.0156, 818us; k_knn 640us @ 5.7% occupancy).
// R7 (4-wave k_knn restructure) regressed to absmax 0.254 (neighbor flips).
// R8: revert to the PROVEN R6 single-wave k_knn body verbatim; gain occupancy
// purely by grid-level chunking: 16 chunks x 256 point-groups = 4096 blocks
// x 64 threads (16 waves/CU). If this fails, chunk math is implicated; if it
// passes, the 4-wave restructure was the bug.
// Folds:
//  - output ref-half rows are exactly zero.
//  - linear chain folds: A = Wout@Wo@Wv [512,256] (bf16), bbig = Wout@(Wo@bv+bo).
//  - d2 matches np f32: rounded products, sequential adds, (d2,idx)-lex ties.
// Scratch: NO d_ws. All scratch inside d_out's dead ref-half regions:
//   g bf16 8MB -> [0,8M); ref4 256K -> [8M,..); idx 512K -> [8.25M,..);
//   Aw 256K -> [8.75M,..); bbig 2K -> [9M,..);  part 16MB -> [32M,48M).
// k_gemm writes pred halves [16M,32M)+[48M,64M); k_zero zeroes ref halves LAST.

#define NRr 8192
#define NPp 8192
#define NC  256
#define NK  8
#define NCH   16     // ref chunks
#define CHUNK 512    // refs per chunk

typedef short bf16x8 __attribute__((ext_vector_type(8)));
typedef float f32x4  __attribute__((ext_vector_type(4)));

__device__ __forceinline__ uint16_t f2bf(float f) {
  uint32_t u = __float_as_uint(f);
  return (uint16_t)((u + 0x7fffu + ((u >> 16) & 1u)) >> 16);
}

// ---------------- prep: ref coords + |r|^2 (literal np rounding) ------------
__global__ void k_prep(const float* __restrict__ xyz_ref, float4* __restrict__ ref4) {
  int i = blockIdx.x * 256 + threadIdx.x;      // 0 .. 2*NR-1
  if (i >= 2 * NRr) return;
  float x = xyz_ref[i*3+0];
  float y = xyz_ref[i*3+1];
  float z = xyz_ref[i*3+2];
  float n = __fadd_rn(__fadd_rn(__fmul_rn(x,x), __fmul_rn(y,y)), __fmul_rn(z,z));
  ref4[i] = make_float4(x, y, z, n);
}

// sorted-8 insert, strict < on d2 (scan order ascending idx => lex-stable)
__device__ __forceinline__ void insert8(float d2, int j, float (&dist)[8], int (&id)[8]) {
  if (d2 < dist[7]) {
    #pragma unroll
    for (int k = 7; k >= 1; --k) {
      bool sh = d2 < dist[k-1];
      bool pl = d2 < dist[k];
      float nd = sh ? dist[k-1] : (pl ? d2 : dist[k]);
      int   ni = sh ? id[k-1]   : (pl ? j  : id[k]);
      dist[k] = nd; id[k] = ni;
    }
    if (d2 < dist[0]) { dist[0] = d2; id[0] = j; }
  }
}

// -------- brute-force KNN: R6 single-wave body, 16 chunks via grid ----------
__global__ __launch_bounds__(64) void k_knn(const float* __restrict__ xyz_pred,
                                            const float4* __restrict__ ref4,
                                            float2* __restrict__ part) {
  __shared__ __align__(16) float4 sref[CHUNK];
  int blk = blockIdx.x;                        // 0..4095
  int ch  = blk & (NCH - 1);                   // 0..15
  int P   = (blk >> 4) * 64 + threadIdx.x;     // global point 0..16383
  int b   = P >> 13;

  float px = xyz_pred[P*3+0];
  float py = xyz_pred[P*3+1];
  float pz = xyz_pred[P*3+2];
  float sp = __fadd_rn(__fadd_rn(__fmul_rn(px,px), __fmul_rn(py,py)), __fmul_rn(pz,pz));

  float dist[8]; int id[8];
  #pragma unroll
  for (int k = 0; k < 8; ++k) { dist[k] = 3.4e38f; id[k] = 0; }

  const float4* refbase = ref4 + (size_t)b * NRr;
  int rbase = ch * CHUNK;

  for (int j = threadIdx.x; j < CHUNK; j += 64) sref[j] = refbase[rbase + j];
  __syncthreads();
  for (int j = 0; j < CHUNK; j += 2) {
    float4 r0 = sref[j];
    float4 r1 = sref[j+1];
    float d0, d1;
    {
      float m0 = __fmul_rn(px, r0.x), m1 = __fmul_rn(py, r0.y), m2 = __fmul_rn(pz, r0.z);
      float dot = __fadd_rn(__fadd_rn(m0, m1), m2);
      d0 = __fsub_rn(__fadd_rn(sp, r0.w), __fadd_rn(dot, dot));
    }
    {
      float m0 = __fmul_rn(px, r1.x), m1 = __fmul_rn(py, r1.y), m2 = __fmul_rn(pz, r1.z);
      float dot = __fadd_rn(__fadd_rn(m0, m1), m2);
      d1 = __fsub_rn(__fadd_rn(sp, r1.w), __fadd_rn(dot, dot));
    }
    if (d0 < dist[7] || d1 < dist[7]) {
      insert8(d0, rbase + j,     dist, id);
      insert8(d1, rbase + j + 1, dist, id);
    }
  }
  float2* pp = part + ((size_t)P * NCH + ch) * 8;
  #pragma unroll
  for (int k = 0; k < 8; ++k)
    pp[k] = make_float2(dist[k], __int_as_float(id[k] & (NRr - 1)));
}

// lex (d2, idx) insert for the merge of the chunk partials
__device__ __forceinline__ void insert_lex(float d2, int j, float (&dist)[8], int (&id)[8]) {
  bool b7 = (d2 < dist[7]) || (d2 == dist[7] && j < id[7]);
  if (b7) {
    #pragma unroll
    for (int k = 7; k >= 1; --k) {
      bool sh = (d2 < dist[k-1]) || (d2 == dist[k-1] && j < id[k-1]);
      bool pl = (d2 < dist[k])   || (d2 == dist[k]   && j < id[k]);
      float nd = sh ? dist[k-1] : (pl ? d2 : dist[k]);
      int   ni = sh ? id[k-1]   : (pl ? j  : id[k]);
      dist[k] = nd; id[k] = ni;
    }
    bool p0 = (d2 < dist[0]) || (d2 == dist[0] && j < id[0]);
    if (p0) { dist[0] = d2; id[0] = j; }
  }
}

__global__ void k_merge(const float2* __restrict__ part, int* __restrict__ idx) {
  int P = blockIdx.x * 256 + threadIdx.x;   // 0..16383
  float dist[8]; int id[8];
  #pragma unroll
  for (int k = 0; k < 8; ++k) { dist[k] = 3.4e38f; id[k] = NRr - 1; }
  const float2* pp = part + (size_t)P * (NCH * 8);
  for (int c = 0; c < NCH * 8; ++c) {
    float2 v = pp[c];
    insert_lex(v.x, __float_as_int(v.y) & (NRr - 1), dist, id);
  }
  #pragma unroll
  for (int k = 0; k < 8; ++k) idx[(size_t)P*8 + k] = id[k] & (NRr - 1);
}

// ---------------- fold Wout@Wo@Wv -> A [512,256] bf16, bbig f32 -------------
__global__ __launch_bounds__(256) void k_combine(const float* __restrict__ Wv,
    const float* __restrict__ bv, const float* __restrict__ Wo,
    const float* __restrict__ bo, const float* __restrict__ Wout,
    uint16_t* __restrict__ Aw, float* __restrict__ bbig) {
  __shared__ float M[256];
  __shared__ float red[256];
  int e = blockIdx.x;      // 0..511
  int t = threadIdx.x;     // 0..255
  float acc = 0.f;
  for (int d = 0; d < 256; ++d)
    acc = fmaf(Wout[(size_t)e*256 + d], Wo[(size_t)d*256 + t], acc);
  M[t] = acc;
  red[t] = fmaf(acc, bv[t], Wout[(size_t)e*256 + t] * bo[t]);
  __syncthreads();
  float a2 = 0.f;
  for (int c = 0; c < 256; ++c)
    a2 = fmaf(M[c], Wv[(size_t)c*256 + t], a2);
  Aw[(size_t)e*256 + t] = f2bf(a2);
  for (int s2 = 128; s2 > 0; s2 >>= 1) {
    if (t < s2) red[t] += red[t + s2];
    __syncthreads();
  }
  if (t == 0) bbig[e] = red[0];
}

// ---------------- attention: one wave per pred point ------------------------
__global__ __launch_bounds__(256) void k_attn(const float* __restrict__ feat_q,
    const float* __restrict__ feat_k, const float* __restrict__ feat_v,
    const int* __restrict__ idx, uint16_t* __restrict__ g) {
  int wave = threadIdx.x >> 6;
  int lane = threadIdx.x & 63;
  int P = blockIdx.x * 4 + wave;     // 0..16383
  int b = P >> 13;
  const int* ip = idx + (size_t)P * 8;
  int nb[8];
  #pragma unroll
  for (int k = 0; k < 8; ++k) nb[k] = ip[k] & (NRr - 1);

  float4 qv = *(const float4*)(feat_q + (size_t)P*NC + lane*4);
  const float* kb = feat_k + (size_t)b * NRr * NC;
  const float* vb = feat_v + (size_t)b * NRr * NC;

  float s[8];
  #pragma unroll
  for (int k = 0; k < 8; ++k) {
    float4 kv = *(const float4*)(kb + (size_t)nb[k]*NC + lane*4);
    float p = qv.x * kv.x;
    p = fmaf(qv.y, kv.y, p);
    p = fmaf(qv.z, kv.z, p);
    p = fmaf(qv.w, kv.w, p);
    s[k] = p;
  }
  #pragma unroll
  for (int k = 0; k < 8; ++k) {
    float v = s[k];
    #pragma unroll
    for (int m = 1; m < 64; m <<= 1) v += __shfl_xor(v, m, 64);
    s[k] = v * 0.0625f;   // / sqrt(256), exact
  }
  float mx = s[0];
  #pragma unroll
  for (int k = 1; k < 8; ++k) mx = fmaxf(mx, s[k]);
  float e[8], sum = 0.f;
  #pragma unroll
  for (int k = 0; k < 8; ++k) { e[k] = expf(s[k] - mx); sum += e[k]; }
  float inv = 1.0f / sum;

  float g0 = 0.f, g1 = 0.f, g2 = 0.f, g3 = 0.f;
  #pragma unroll
  for (int k = 0; k < 8; ++k) {
    float4 vv = *(const float4*)(vb + (size_t)nb[k]*NC + lane*4);
    float w = e[k] * inv;
    g0 = fmaf(w, vv.x, g0);
    g1 = fmaf(w, vv.y, g1);
    g2 = fmaf(w, vv.z, g2);
    g3 = fmaf(w, vv.w, g3);
  }
  uint32_t p0 = ((uint32_t)f2bf(g1) << 16) | f2bf(g0);
  uint32_t p1 = ((uint32_t)f2bf(g3) << 16) | f2bf(g2);
  *(uint2*)(g + (size_t)P*NC + lane*4) = make_uint2(p0, p1);
}

// ---------------- zero-fill ref halves of output (runs LAST) ----------------
__global__ void k_zero(float4* __restrict__ o) {
  int i = blockIdx.x * 256 + threadIdx.x;  // 0 .. 2097151
  int b = i >> 20;                         // region 0 or 1
  int r = i & 1048575;                     // 1M float4 per 16MB region
  o[(size_t)b * 2097152 + r] = make_float4(0.f, 0.f, 0.f, 0.f);
}

// ---------------- final GEMM: g[16384,256]bf16 @ A^T + bbig -> f32 ----------
__global__ __launch_bounds__(256) void k_gemm(const uint16_t* __restrict__ g,
    const uint16_t* __restrict__ Aw, const float* __restrict__ bbig,
    float* __restrict__ outp) {
  // LDS stride 136 (272B): 16B-aligned rows, 4-bank shift/row => conflict-free
  __shared__ __align__(16) uint16_t sA[64 * 136];
  __shared__ __align__(16) uint16_t sB[64 * 136];
  int t = threadIdx.x;
  int lane = t & 63, wave = t >> 6;
  int wm = (wave >> 1) * 32, wn = (wave & 1) * 32;
  int q = lane >> 4, rr = lane & 15;
  int bm = blockIdx.x;   // 0..255 (M tiles of 64)
  int bn = blockIdx.y;   // 0..7   (N tiles of 64)
  f32x4 zero = {0.f, 0.f, 0.f, 0.f};
  f32x4 acc[2][2] = {{zero, zero}, {zero, zero}};

  for (int ph = 0; ph < 2; ++ph) {      // K = 256 in two 128 phases
    #pragma unroll
    for (int i = 0; i < 4; ++i) {
      int cc  = t + i * 256;            // 0..1023 chunks of 8 bf16
      int row = cc >> 4;                // 16 chunks per row
      int col = (cc & 15) << 3;
      uint4 da = *(const uint4*)(g  + ((size_t)(bm*64 + row))*NC + ph*128 + col);
      *(uint4*)(&sA[row*136 + col]) = da;
      uint4 db = *(const uint4*)(Aw + ((size_t)(bn*64 + row))*NC + ph*128 + col);
      *(uint4*)(&sB[row*136 + col]) = db;
    }
    __syncthreads();
    #pragma unroll
    for (int kk = 0; kk < 4; ++kk) {
      int ko = kk*32 + q*8;
      bf16x8 a0 = *(const bf16x8*)(&sA[(wm      + rr)*136 + ko]);
      bf16x8 a1 = *(const bf16x8*)(&sA[(wm + 16 + rr)*136 + ko]);
      bf16x8 b0 = *(const bf16x8*)(&sB[(wn      + rr)*136 + ko]);
      bf16x8 b1 = *(const bf16x8*)(&sB[(wn + 16 + rr)*136 + ko]);
      acc[0][0] = __builtin_amdgcn_mfma_f32_16x16x32_bf16(a0, b0, acc[0][0], 0, 0, 0);
      acc[0][1] = __builtin_amdgcn_mfma_f32_16x16x32_bf16(a0, b1, acc[0][1], 0, 0, 0);
      acc[1][0] = __builtin_amdgcn_mfma_f32_16x16x32_bf16(a1, b0, acc[1][0], 0, 0, 0);
      acc[1][1] = __builtin_amdgcn_mfma_f32_16x16x32_bf16(a1, b1, acc[1][1], 0, 0, 0);
    }
    __syncthreads();
  }
  #pragma unroll
  for (int j = 0; j < 2; ++j) {
    int col = bn*64 + wn + j*16 + rr;
    float bias = bbig[col];
    #pragma unroll
    for (int i = 0; i < 2; ++i) {
      #pragma unroll
      for (int r = 0; r < 4; ++r) {
        int row = bm*64 + wm + i*16 + q*4 + r;   // C/D: col=lane&15, row=(lane>>4)*4+reg
        float v = acc[i][j][r] + bias;
        int bb = row >> 13, p = row & 8191;
        outp[((size_t)(bb*16384 + 8192 + p))*512 + col] = v;
      }
    }
  }
}

extern "C" void kernel_launch(void* const* d_in, const int* in_sizes, int n_in,
                              void* d_out, int out_size, void* d_ws, size_t ws_size,
                              hipStream_t stream) {
  const float* xyz_ref  = (const float*)d_in[0];
  const float* xyz_pred = (const float*)d_in[1];
  const float* feat_k   = (const float*)d_in[2];
  const float* feat_q   = (const float*)d_in[3];
  const float* feat_v   = (const float*)d_in[4];
  const float* Wv       = (const float*)d_in[5];
  const float* bv       = (const float*)d_in[6];
  const float* Wo       = (const float*)d_in[7];
  const float* bo       = (const float*)d_in[8];
  const float* Wout     = (const float*)d_in[9];
  float* outp = (float*)d_out;

  // ALL scratch inside d_out's dead ref-half regions (f32 output, 64MB):
  char* ob = (char*)d_out;
  uint16_t* g    = (uint16_t*)ob;                    // [0, 8M)    bf16 16384x256
  float4*   ref4 = (float4*)(ob + 8388608);          // [8M, 8.25M)
  int*      idx  = (int*)(ob + 8650752);             // [8.25M, 8.75M)
  uint16_t* Aw   = (uint16_t*)(ob + 9175040);        // [8.75M, 9M)
  float*    bbig = (float*)(ob + 9437184);           // [9M, +2K)
  float2*   part = (float2*)(ob + 33554432);         // [32M, 48M)  16 MB

  k_prep   <<<64,   256, 0, stream>>>(xyz_ref, ref4);
  k_knn    <<<4096, 64,  0, stream>>>(xyz_pred, ref4, part);
  k_merge  <<<64,   256, 0, stream>>>(part, idx);
  k_combine<<<512,  256, 0, stream>>>(Wv, bv, Wo, bo, Wout, Aw, bbig);
  k_attn   <<<4096, 256, 0, stream>>>(feat_q, feat_k, feat_v, idx, g);
  k_gemm   <<<dim3(256, 8), 256, 0, stream>>>(g, Aw, bbig, outp);
  k_zero   <<<8192, 256, 0, stream>>>((float4*)outp);
}

// Round 9
// 521.873 us; speedup vs baseline: 1.5676x; 1.0017x over previous
//
#include <hip/hip_runtime.h>
#include <stdint.h>

// CrossAttn: B=2, Nr=Np=8192, C=256, K=8. ALL I/O float32.
// R8 passed 522us (k_knn 303us @ 30.7% occ, VALUBusy 77%). R9:
//  - k_knn: NCH=32/CHUNK=256, grid 8192x64 -> 32 waves/CU (occupancy cap).
//    Body verbatim R8; epilogue stores u16 indices only (part 8MB).
//  - k_merge: recomputes d2 bit-exactly (shared d2f helper) + lex merge.
//  - k_combine: 64 blocks x 8 rows, register reuse (268MB -> 33MB reads).
// R7 lesson: single-wave k_knn body is the trusted shape; do not re-wave it.
// Scratch: NO d_ws. All inside d_out dead ref-half regions:
//   g 8MB [0,8M); ref4 [8M,..); idx [8.25M,..); Aw [8.75M,..); bbig [9M,..);
//   part u16 8MB [32M,40M).
// k_gemm writes pred halves [16M,32M)+[48M,64M); k_zero zeroes ref halves LAST.

#define NRr 8192
#define NPp 8192
#define NC  256
#define NK  8
#define NCH   32     // ref chunks
#define CHUNK 256    // refs per chunk

typedef short bf16x8 __attribute__((ext_vector_type(8)));
typedef float f32x4  __attribute__((ext_vector_type(4)));

__device__ __forceinline__ uint16_t f2bf(float f) {
  uint32_t u = __float_as_uint(f);
  return (uint16_t)((u + 0x7fffu + ((u >> 16) & 1u)) >> 16);
}

// Exact np-f32 d2: rounded products, sequential adds, (sp+sr) - (dot+dot).
// Used by BOTH k_knn and k_merge so recomputation is bitwise identical.
__device__ __forceinline__ float d2f(float px, float py, float pz, float sp, float4 r) {
  float m0 = __fmul_rn(px, r.x), m1 = __fmul_rn(py, r.y), m2 = __fmul_rn(pz, r.z);
  float dot = __fadd_rn(__fadd_rn(m0, m1), m2);
  return __fsub_rn(__fadd_rn(sp, r.w), __fadd_rn(dot, dot));
}

// ---------------- prep: ref coords + |r|^2 (literal np rounding) ------------
__global__ void k_prep(const float* __restrict__ xyz_ref, float4* __restrict__ ref4) {
  int i = blockIdx.x * 256 + threadIdx.x;      // 0 .. 2*NR-1
  if (i >= 2 * NRr) return;
  float x = xyz_ref[i*3+0];
  float y = xyz_ref[i*3+1];
  float z = xyz_ref[i*3+2];
  float n = __fadd_rn(__fadd_rn(__fmul_rn(x,x), __fmul_rn(y,y)), __fmul_rn(z,z));
  ref4[i] = make_float4(x, y, z, n);
}

// sorted-8 insert, strict < on d2 (scan order ascending idx => lex-stable)
__device__ __forceinline__ void insert8(float d2, int j, float (&dist)[8], int (&id)[8]) {
  if (d2 < dist[7]) {
    #pragma unroll
    for (int k = 7; k >= 1; --k) {
      bool sh = d2 < dist[k-1];
      bool pl = d2 < dist[k];
      float nd = sh ? dist[k-1] : (pl ? d2 : dist[k]);
      int   ni = sh ? id[k-1]   : (pl ? j  : id[k]);
      dist[k] = nd; id[k] = ni;
    }
    if (d2 < dist[0]) { dist[0] = d2; id[0] = j; }
  }
}

// -------- brute-force KNN: R8 single-wave body, 32 chunks via grid ----------
__global__ __launch_bounds__(64) void k_knn(const float* __restrict__ xyz_pred,
                                            const float4* __restrict__ ref4,
                                            uint16_t* __restrict__ part) {
  __shared__ __align__(16) float4 sref[CHUNK];
  int blk = blockIdx.x;                        // 0..8191
  int ch  = blk & (NCH - 1);                   // 0..31
  int P   = (blk >> 5) * 64 + threadIdx.x;     // global point 0..16383
  int b   = P >> 13;

  float px = xyz_pred[P*3+0];
  float py = xyz_pred[P*3+1];
  float pz = xyz_pred[P*3+2];
  float sp = __fadd_rn(__fadd_rn(__fmul_rn(px,px), __fmul_rn(py,py)), __fmul_rn(pz,pz));

  float dist[8]; int id[8];
  #pragma unroll
  for (int k = 0; k < 8; ++k) { dist[k] = 3.4e38f; id[k] = 0; }

  const float4* refbase = ref4 + (size_t)b * NRr;
  int rbase = ch * CHUNK;

  for (int j = threadIdx.x; j < CHUNK; j += 64) sref[j] = refbase[rbase + j];
  __syncthreads();
  for (int j = 0; j < CHUNK; j += 2) {
    float4 r0 = sref[j];
    float4 r1 = sref[j+1];
    float d0 = d2f(px, py, pz, sp, r0);
    float d1 = d2f(px, py, pz, sp, r1);
    if (d0 < dist[7] || d1 < dist[7]) {
      insert8(d0, rbase + j,     dist, id);
      insert8(d1, rbase + j + 1, dist, id);
    }
  }
  uint16_t* pp = part + ((size_t)P * NCH + ch) * 8;
  #pragma unroll
  for (int k = 0; k < 8; ++k)
    pp[k] = (uint16_t)(id[k] & (NRr - 1));
}

// lex (d2, idx) insert for the merge of the chunk partials
__device__ __forceinline__ void insert_lex(float d2, int j, float (&dist)[8], int (&id)[8]) {
  bool b7 = (d2 < dist[7]) || (d2 == dist[7] && j < id[7]);
  if (b7) {
    #pragma unroll
    for (int k = 7; k >= 1; --k) {
      bool sh = (d2 < dist[k-1]) || (d2 == dist[k-1] && j < id[k-1]);
      bool pl = (d2 < dist[k])   || (d2 == dist[k]   && j < id[k]);
      float nd = sh ? dist[k-1] : (pl ? d2 : dist[k]);
      int   ni = sh ? id[k-1]   : (pl ? j  : id[k]);
      dist[k] = nd; id[k] = ni;
    }
    bool p0 = (d2 < dist[0]) || (d2 == dist[0] && j < id[0]);
    if (p0) { dist[0] = d2; id[0] = j; }
  }
}

// merge: recompute d2 exactly from ref4 (d2f) for the 256 u16 candidates
__global__ __launch_bounds__(256) void k_merge(const uint16_t* __restrict__ part,
                                               const float* __restrict__ xyz_pred,
                                               const float4* __restrict__ ref4,
                                               int* __restrict__ idx) {
  int P = blockIdx.x * 256 + threadIdx.x;   // 0..16383
  int b = P >> 13;
  float px = xyz_pred[P*3+0];
  float py = xyz_pred[P*3+1];
  float pz = xyz_pred[P*3+2];
  float sp = __fadd_rn(__fadd_rn(__fmul_rn(px,px), __fmul_rn(py,py)), __fmul_rn(pz,pz));
  const float4* refbase = ref4 + (size_t)b * NRr;

  float dist[8]; int id[8];
  #pragma unroll
  for (int k = 0; k < 8; ++k) { dist[k] = 3.4e38f; id[k] = NRr - 1; }

  const ushort4* pv = (const ushort4*)(part + (size_t)P * (NCH * 8));
  for (int c = 0; c < NCH * 2; ++c) {        // 64 x ushort4 = 256 candidates
    ushort4 v = pv[c];
    int j0 = v.x & (NRr - 1), j1 = v.y & (NRr - 1);
    int j2 = v.z & (NRr - 1), j3 = v.w & (NRr - 1);
    insert_lex(d2f(px, py, pz, sp, refbase[j0]), j0, dist, id);
    insert_lex(d2f(px, py, pz, sp, refbase[j1]), j1, dist, id);
    insert_lex(d2f(px, py, pz, sp, refbase[j2]), j2, dist, id);
    insert_lex(d2f(px, py, pz, sp, refbase[j3]), j3, dist, id);
  }
  #pragma unroll
  for (int k = 0; k < 8; ++k) idx[(size_t)P*8 + k] = id[k] & (NRr - 1);
}

// ------- fold Wout@Wo@Wv -> A [512,256] bf16, bbig f32 (8 rows/block) -------
__global__ __launch_bounds__(256) void k_combine(const float* __restrict__ Wv,
    const float* __restrict__ bv, const float* __restrict__ Wo,
    const float* __restrict__ bo, const float* __restrict__ Wout,
    uint16_t* __restrict__ Aw, float* __restrict__ bbig) {
  __shared__ float M8[8][256];
  __shared__ float red[256];
  int e0 = blockIdx.x * 8;   // 0..511 in groups of 8
  int t  = threadIdx.x;      // 0..255

  float acc8[8];
  #pragma unroll
  for (int e = 0; e < 8; ++e) acc8[e] = 0.f;
  for (int d = 0; d < 256; ++d) {
    float wo = Wo[(size_t)d*256 + t];
    #pragma unroll
    for (int e = 0; e < 8; ++e)
      acc8[e] = fmaf(Wout[(size_t)(e0+e)*256 + d], wo, acc8[e]);
  }
  #pragma unroll
  for (int e = 0; e < 8; ++e) M8[e][t] = acc8[e];
  __syncthreads();

  float a8[8];
  #pragma unroll
  for (int e = 0; e < 8; ++e) a8[e] = 0.f;
  for (int c = 0; c < 256; ++c) {
    float wv = Wv[(size_t)c*256 + t];
    #pragma unroll
    for (int e = 0; e < 8; ++e)
      a8[e] = fmaf(M8[e][c], wv, a8[e]);
  }
  #pragma unroll
  for (int e = 0; e < 8; ++e) Aw[(size_t)(e0+e)*256 + t] = f2bf(a8[e]);

  for (int e = 0; e < 8; ++e) {
    red[t] = fmaf(M8[e][t], bv[t], Wout[(size_t)(e0+e)*256 + t] * bo[t]);
    __syncthreads();
    for (int s2 = 128; s2 > 0; s2 >>= 1) {
      if (t < s2) red[t] += red[t + s2];
      __syncthreads();
    }
    if (t == 0) bbig[e0+e] = red[0];
    __syncthreads();
  }
}

// ---------------- attention: one wave per pred point ------------------------
__global__ __launch_bounds__(256) void k_attn(const float* __restrict__ feat_q,
    const float* __restrict__ feat_k, const float* __restrict__ feat_v,
    const int* __restrict__ idx, uint16_t* __restrict__ g) {
  int wave = threadIdx.x >> 6;
  int lane = threadIdx.x & 63;
  int P = blockIdx.x * 4 + wave;     // 0..16383
  int b = P >> 13;
  const int* ip = idx + (size_t)P * 8;
  int nb[8];
  #pragma unroll
  for (int k = 0; k < 8; ++k) nb[k] = ip[k] & (NRr - 1);

  float4 qv = *(const float4*)(feat_q + (size_t)P*NC + lane*4);
  const float* kb = feat_k + (size_t)b * NRr * NC;
  const float* vb = feat_v + (size_t)b * NRr * NC;

  float s[8];
  #pragma unroll
  for (int k = 0; k < 8; ++k) {
    float4 kv = *(const float4*)(kb + (size_t)nb[k]*NC + lane*4);
    float p = qv.x * kv.x;
    p = fmaf(qv.y, kv.y, p);
    p = fmaf(qv.z, kv.z, p);
    p = fmaf(qv.w, kv.w, p);
    s[k] = p;
  }
  #pragma unroll
  for (int k = 0; k < 8; ++k) {
    float v = s[k];
    #pragma unroll
    for (int m = 1; m < 64; m <<= 1) v += __shfl_xor(v, m, 64);
    s[k] = v * 0.0625f;   // / sqrt(256), exact
  }
  float mx = s[0];
  #pragma unroll
  for (int k = 1; k < 8; ++k) mx = fmaxf(mx, s[k]);
  float e[8], sum = 0.f;
  #pragma unroll
  for (int k = 0; k < 8; ++k) { e[k] = expf(s[k] - mx); sum += e[k]; }
  float inv = 1.0f / sum;

  float g0 = 0.f, g1 = 0.f, g2 = 0.f, g3 = 0.f;
  #pragma unroll
  for (int k = 0; k < 8; ++k) {
    float4 vv = *(const float4*)(vb + (size_t)nb[k]*NC + lane*4);
    float w = e[k] * inv;
    g0 = fmaf(w, vv.x, g0);
    g1 = fmaf(w, vv.y, g1);
    g2 = fmaf(w, vv.z, g2);
    g3 = fmaf(w, vv.w, g3);
  }
  uint32_t p0 = ((uint32_t)f2bf(g1) << 16) | f2bf(g0);
  uint32_t p1 = ((uint32_t)f2bf(g3) << 16) | f2bf(g2);
  *(uint2*)(g + (size_t)P*NC + lane*4) = make_uint2(p0, p1);
}

// ---------------- zero-fill ref halves of output (runs LAST) ----------------
__global__ void k_zero(float4* __restrict__ o) {
  int i = blockIdx.x * 256 + threadIdx.x;  // 0 .. 2097151
  int b = i >> 20;                         // region 0 or 1
  int r = i & 1048575;                     // 1M float4 per 16MB region
  o[(size_t)b * 2097152 + r] = make_float4(0.f, 0.f, 0.f, 0.f);
}

// ---------------- final GEMM: g[16384,256]bf16 @ A^T + bbig -> f32 ----------
__global__ __launch_bounds__(256) void k_gemm(const uint16_t* __restrict__ g,
    const uint16_t* __restrict__ Aw, const float* __restrict__ bbig,
    float* __restrict__ outp) {
  // LDS stride 136 (272B): 16B-aligned rows, 4-bank shift/row => conflict-free
  __shared__ __align__(16) uint16_t sA[64 * 136];
  __shared__ __align__(16) uint16_t sB[64 * 136];
  int t = threadIdx.x;
  int lane = t & 63, wave = t >> 6;
  int wm = (wave >> 1) * 32, wn = (wave & 1) * 32;
  int q = lane >> 4, rr = lane & 15;
  int bm = blockIdx.x;   // 0..255 (M tiles of 64)
  int bn = blockIdx.y;   // 0..7   (N tiles of 64)
  f32x4 zero = {0.f, 0.f, 0.f, 0.f};
  f32x4 acc[2][2] = {{zero, zero}, {zero, zero}};

  for (int ph = 0; ph < 2; ++ph) {      // K = 256 in two 128 phases
    #pragma unroll
    for (int i = 0; i < 4; ++i) {
      int cc  = t + i * 256;            // 0..1023 chunks of 8 bf16
      int row = cc >> 4;                // 16 chunks per row
      int col = (cc & 15) << 3;
      uint4 da = *(const uint4*)(g  + ((size_t)(bm*64 + row))*NC + ph*128 + col);
      *(uint4*)(&sA[row*136 + col]) = da;
      uint4 db = *(const uint4*)(Aw + ((size_t)(bn*64 + row))*NC + ph*128 + col);
      *(uint4*)(&sB[row*136 + col]) = db;
    }
    __syncthreads();
    #pragma unroll
    for (int kk = 0; kk < 4; ++kk) {
      int ko = kk*32 + q*8;
      bf16x8 a0 = *(const bf16x8*)(&sA[(wm      + rr)*136 + ko]);
      bf16x8 a1 = *(const bf16x8*)(&sA[(wm + 16 + rr)*136 + ko]);
      bf16x8 b0 = *(const bf16x8*)(&sB[(wn      + rr)*136 + ko]);
      bf16x8 b1 = *(const bf16x8*)(&sB[(wn + 16 + rr)*136 + ko]);
      acc[0][0] = __builtin_amdgcn_mfma_f32_16x16x32_bf16(a0, b0, acc[0][0], 0, 0, 0);
      acc[0][1] = __builtin_amdgcn_mfma_f32_16x16x32_bf16(a0, b1, acc[0][1], 0, 0, 0);
      acc[1][0] = __builtin_amdgcn_mfma_f32_16x16x32_bf16(a1, b0, acc[1][0], 0, 0, 0);
      acc[1][1] = __builtin_amdgcn_mfma_f32_16x16x32_bf16(a1, b1, acc[1][1], 0, 0, 0);
    }
    __syncthreads();
  }
  #pragma unroll
  for (int j = 0; j < 2; ++j) {
    int col = bn*64 + wn + j*16 + rr;
    float bias = bbig[col];
    #pragma unroll
    for (int i = 0; i < 2; ++i) {
      #pragma unroll
      for (int r = 0; r < 4; ++r) {
        int row = bm*64 + wm + i*16 + q*4 + r;   // C/D: col=lane&15, row=(lane>>4)*4+reg
        float v = acc[i][j][r] + bias;
        int bb = row >> 13, p = row & 8191;
        outp[((size_t)(bb*16384 + 8192 + p))*512 + col] = v;
      }
    }
  }
}

extern "C" void kernel_launch(void* const* d_in, const int* in_sizes, int n_in,
                              void* d_out, int out_size, void* d_ws, size_t ws_size,
                              hipStream_t stream) {
  const float* xyz_ref  = (const float*)d_in[0];
  const float* xyz_pred = (const float*)d_in[1];
  const float* feat_k   = (const float*)d_in[2];
  const float* feat_q   = (const float*)d_in[3];
  const float* feat_v   = (const float*)d_in[4];
  const float* Wv       = (const float*)d_in[5];
  const float* bv       = (const float*)d_in[6];
  const float* Wo       = (const float*)d_in[7];
  const float* bo       = (const float*)d_in[8];
  const float* Wout     = (const float*)d_in[9];
  float* outp = (float*)d_out;

  // ALL scratch inside d_out's dead ref-half regions (f32 output, 64MB):
  char* ob = (char*)d_out;
  uint16_t* g    = (uint16_t*)ob;                    // [0, 8M)    bf16 16384x256
  float4*   ref4 = (float4*)(ob + 8388608);          // [8M, 8.25M)
  int*      idx  = (int*)(ob + 8650752);             // [8.25M, 8.75M)
  uint16_t* Aw   = (uint16_t*)(ob + 9175040);        // [8.75M, 9M)
  float*    bbig = (float*)(ob + 9437184);           // [9M, +2K)
  uint16_t* part = (uint16_t*)(ob + 33554432);       // [32M, 40M)  8 MB u16

  k_prep   <<<64,   256, 0, stream>>>(xyz_ref, ref4);
  k_knn    <<<8192, 64,  0, stream>>>(xyz_pred, ref4, part);
  k_merge  <<<64,   256, 0, stream>>>(part, xyz_pred, ref4, idx);
  k_combine<<<64,   256, 0, stream>>>(Wv, bv, Wo, bo, Wout, Aw, bbig);
  k_attn   <<<4096, 256, 0, stream>>>(feat_q, feat_k, feat_v, idx, g);
  k_gemm   <<<dim3(256, 8), 256, 0, stream>>>(g, Aw, bbig, outp);
  k_zero   <<<8192, 256, 0, stream>>>((float4*)outp);
}

// Round 10
// 512.987 us; speedup vs baseline: 1.5947x; 1.0173x over previous
//
#include <hip/hip_runtime.h>
#include <stdint.h>

// CrossAttn: B=2, Nr=Np=8192, C=256, K=8. ALL I/O float32.
// R9: 522us total; k_knn 222us @ 60% occ (WG/CU dispatch limit with 64-thread
// blocks), VALU-saturated. R10: k_knn packs 4 INDEPENDENT single-wave bodies
// per 256-thread block with wave-PRIVATE LDS segments (no __syncthreads, no
// cross-wave coupling -- unlike failed R7). 8 blocks/CU x 4 waves = 32/32.
// Body is verbatim R9 per wave. Everything else unchanged from R9.
// Scratch: NO d_ws. All inside d_out dead ref-half regions:
//   g 8MB [0,8M); ref4 [8M,..); idx [8.25M,..); Aw [8.75M,..); bbig [9M,..);
//   part u16 8MB [32M,40M).
// k_gemm writes pred halves [16M,32M)+[48M,64M); k_zero zeroes ref halves LAST.

#define NRr 8192
#define NPp 8192
#define NC  256
#define NK  8
#define NCH   32     // ref chunks
#define CHUNK 256    // refs per chunk

typedef short bf16x8 __attribute__((ext_vector_type(8)));
typedef float f32x4  __attribute__((ext_vector_type(4)));

__device__ __forceinline__ uint16_t f2bf(float f) {
  uint32_t u = __float_as_uint(f);
  return (uint16_t)((u + 0x7fffu + ((u >> 16) & 1u)) >> 16);
}

// Exact np-f32 d2: rounded products, sequential adds, (sp+sr) - (dot+dot).
// Used by BOTH k_knn and k_merge so recomputation is bitwise identical.
__device__ __forceinline__ float d2f(float px, float py, float pz, float sp, float4 r) {
  float m0 = __fmul_rn(px, r.x), m1 = __fmul_rn(py, r.y), m2 = __fmul_rn(pz, r.z);
  float dot = __fadd_rn(__fadd_rn(m0, m1), m2);
  return __fsub_rn(__fadd_rn(sp, r.w), __fadd_rn(dot, dot));
}

// ---------------- prep: ref coords + |r|^2 (literal np rounding) ------------
__global__ void k_prep(const float* __restrict__ xyz_ref, float4* __restrict__ ref4) {
  int i = blockIdx.x * 256 + threadIdx.x;      // 0 .. 2*NR-1
  if (i >= 2 * NRr) return;
  float x = xyz_ref[i*3+0];
  float y = xyz_ref[i*3+1];
  float z = xyz_ref[i*3+2];
  float n = __fadd_rn(__fadd_rn(__fmul_rn(x,x), __fmul_rn(y,y)), __fmul_rn(z,z));
  ref4[i] = make_float4(x, y, z, n);
}

// sorted-8 insert, strict < on d2 (scan order ascending idx => lex-stable)
__device__ __forceinline__ void insert8(float d2, int j, float (&dist)[8], int (&id)[8]) {
  if (d2 < dist[7]) {
    #pragma unroll
    for (int k = 7; k >= 1; --k) {
      bool sh = d2 < dist[k-1];
      bool pl = d2 < dist[k];
      float nd = sh ? dist[k-1] : (pl ? d2 : dist[k]);
      int   ni = sh ? id[k-1]   : (pl ? j  : id[k]);
      dist[k] = nd; id[k] = ni;
    }
    if (d2 < dist[0]) { dist[0] = d2; id[0] = j; }
  }
}

// ---- brute-force KNN: 4 independent single-wave bodies per 256-thr block ---
// wave-task = blockIdx*4 + wave; ch = task & 31; point-group = task >> 5.
// Each wave stages its OWN 4KB LDS segment and never reads another wave's:
// no barrier, no cross-wave coupling (R7 failure mode structurally excluded).
__global__ __launch_bounds__(256) void k_knn(const float* __restrict__ xyz_pred,
                                             const float4* __restrict__ ref4,
                                             uint16_t* __restrict__ part) {
  __shared__ __align__(16) float4 sref[4][CHUNK];
  int wave = threadIdx.x >> 6;
  int lane = threadIdx.x & 63;
  int task = blockIdx.x * 4 + wave;            // 0..8191
  int ch   = task & (NCH - 1);                 // 0..31
  int P    = (task >> 5) * 64 + lane;          // global point 0..16383
  int b    = P >> 13;

  float px = xyz_pred[P*3+0];
  float py = xyz_pred[P*3+1];
  float pz = xyz_pred[P*3+2];
  float sp = __fadd_rn(__fadd_rn(__fmul_rn(px,px), __fmul_rn(py,py)), __fmul_rn(pz,pz));

  float dist[8]; int id[8];
  #pragma unroll
  for (int k = 0; k < 8; ++k) { dist[k] = 3.4e38f; id[k] = 0; }

  const float4* refbase = ref4 + (size_t)b * NRr;
  int rbase = ch * CHUNK;

  for (int j = lane; j < CHUNK; j += 64) sref[wave][j] = refbase[rbase + j];
  // no __syncthreads: in-wave ds_write -> ds_read ordering via lgkmcnt
  for (int j = 0; j < CHUNK; j += 2) {
    float4 r0 = sref[wave][j];
    float4 r1 = sref[wave][j+1];
    float d0 = d2f(px, py, pz, sp, r0);
    float d1 = d2f(px, py, pz, sp, r1);
    if (d0 < dist[7] || d1 < dist[7]) {
      insert8(d0, rbase + j,     dist, id);
      insert8(d1, rbase + j + 1, dist, id);
    }
  }
  uint16_t* pp = part + ((size_t)P * NCH + ch) * 8;
  #pragma unroll
  for (int k = 0; k < 8; ++k)
    pp[k] = (uint16_t)(id[k] & (NRr - 1));
}

// lex (d2, idx) insert for the merge of the chunk partials
__device__ __forceinline__ void insert_lex(float d2, int j, float (&dist)[8], int (&id)[8]) {
  bool b7 = (d2 < dist[7]) || (d2 == dist[7] && j < id[7]);
  if (b7) {
    #pragma unroll
    for (int k = 7; k >= 1; --k) {
      bool sh = (d2 < dist[k-1]) || (d2 == dist[k-1] && j < id[k-1]);
      bool pl = (d2 < dist[k])   || (d2 == dist[k]   && j < id[k]);
      float nd = sh ? dist[k-1] : (pl ? d2 : dist[k]);
      int   ni = sh ? id[k-1]   : (pl ? j  : id[k]);
      dist[k] = nd; id[k] = ni;
    }
    bool p0 = (d2 < dist[0]) || (d2 == dist[0] && j < id[0]);
    if (p0) { dist[0] = d2; id[0] = j; }
  }
}

// merge: recompute d2 exactly from ref4 (d2f) for the 256 u16 candidates
__global__ __launch_bounds__(256) void k_merge(const uint16_t* __restrict__ part,
                                               const float* __restrict__ xyz_pred,
                                               const float4* __restrict__ ref4,
                                               int* __restrict__ idx) {
  int P = blockIdx.x * 256 + threadIdx.x;   // 0..16383
  int b = P >> 13;
  float px = xyz_pred[P*3+0];
  float py = xyz_pred[P*3+1];
  float pz = xyz_pred[P*3+2];
  float sp = __fadd_rn(__fadd_rn(__fmul_rn(px,px), __fmul_rn(py,py)), __fmul_rn(pz,pz));
  const float4* refbase = ref4 + (size_t)b * NRr;

  float dist[8]; int id[8];
  #pragma unroll
  for (int k = 0; k < 8; ++k) { dist[k] = 3.4e38f; id[k] = NRr - 1; }

  const ushort4* pv = (const ushort4*)(part + (size_t)P * (NCH * 8));
  for (int c = 0; c < NCH * 2; ++c) {        // 64 x ushort4 = 256 candidates
    ushort4 v = pv[c];
    int j0 = v.x & (NRr - 1), j1 = v.y & (NRr - 1);
    int j2 = v.z & (NRr - 1), j3 = v.w & (NRr - 1);
    insert_lex(d2f(px, py, pz, sp, refbase[j0]), j0, dist, id);
    insert_lex(d2f(px, py, pz, sp, refbase[j1]), j1, dist, id);
    insert_lex(d2f(px, py, pz, sp, refbase[j2]), j2, dist, id);
    insert_lex(d2f(px, py, pz, sp, refbase[j3]), j3, dist, id);
  }
  #pragma unroll
  for (int k = 0; k < 8; ++k) idx[(size_t)P*8 + k] = id[k] & (NRr - 1);
}

// ------- fold Wout@Wo@Wv -> A [512,256] bf16, bbig f32 (8 rows/block) -------
__global__ __launch_bounds__(256) void k_combine(const float* __restrict__ Wv,
    const float* __restrict__ bv, const float* __restrict__ Wo,
    const float* __restrict__ bo, const float* __restrict__ Wout,
    uint16_t* __restrict__ Aw, float* __restrict__ bbig) {
  __shared__ float M8[8][256];
  __shared__ float red[256];
  int e0 = blockIdx.x * 8;   // 0..511 in groups of 8
  int t  = threadIdx.x;      // 0..255

  float acc8[8];
  #pragma unroll
  for (int e = 0; e < 8; ++e) acc8[e] = 0.f;
  for (int d = 0; d < 256; ++d) {
    float wo = Wo[(size_t)d*256 + t];
    #pragma unroll
    for (int e = 0; e < 8; ++e)
      acc8[e] = fmaf(Wout[(size_t)(e0+e)*256 + d], wo, acc8[e]);
  }
  #pragma unroll
  for (int e = 0; e < 8; ++e) M8[e][t] = acc8[e];
  __syncthreads();

  float a8[8];
  #pragma unroll
  for (int e = 0; e < 8; ++e) a8[e] = 0.f;
  for (int c = 0; c < 256; ++c) {
    float wv = Wv[(size_t)c*256 + t];
    #pragma unroll
    for (int e = 0; e < 8; ++e)
      a8[e] = fmaf(M8[e][c], wv, a8[e]);
  }
  #pragma unroll
  for (int e = 0; e < 8; ++e) Aw[(size_t)(e0+e)*256 + t] = f2bf(a8[e]);

  for (int e = 0; e < 8; ++e) {
    red[t] = fmaf(M8[e][t], bv[t], Wout[(size_t)(e0+e)*256 + t] * bo[t]);
    __syncthreads();
    for (int s2 = 128; s2 > 0; s2 >>= 1) {
      if (t < s2) red[t] += red[t + s2];
      __syncthreads();
    }
    if (t == 0) bbig[e0+e] = red[0];
    __syncthreads();
  }
}

// ---------------- attention: one wave per pred point ------------------------
__global__ __launch_bounds__(256) void k_attn(const float* __restrict__ feat_q,
    const float* __restrict__ feat_k, const float* __restrict__ feat_v,
    const int* __restrict__ idx, uint16_t* __restrict__ g) {
  int wave = threadIdx.x >> 6;
  int lane = threadIdx.x & 63;
  int P = blockIdx.x * 4 + wave;     // 0..16383
  int b = P >> 13;
  const int* ip = idx + (size_t)P * 8;
  int nb[8];
  #pragma unroll
  for (int k = 0; k < 8; ++k) nb[k] = ip[k] & (NRr - 1);

  float4 qv = *(const float4*)(feat_q + (size_t)P*NC + lane*4);
  const float* kb = feat_k + (size_t)b * NRr * NC;
  const float* vb = feat_v + (size_t)b * NRr * NC;

  float s[8];
  #pragma unroll
  for (int k = 0; k < 8; ++k) {
    float4 kv = *(const float4*)(kb + (size_t)nb[k]*NC + lane*4);
    float p = qv.x * kv.x;
    p = fmaf(qv.y, kv.y, p);
    p = fmaf(qv.z, kv.z, p);
    p = fmaf(qv.w, kv.w, p);
    s[k] = p;
  }
  #pragma unroll
  for (int k = 0; k < 8; ++k) {
    float v = s[k];
    #pragma unroll
    for (int m = 1; m < 64; m <<= 1) v += __shfl_xor(v, m, 64);
    s[k] = v * 0.0625f;   // / sqrt(256), exact
  }
  float mx = s[0];
  #pragma unroll
  for (int k = 1; k < 8; ++k) mx = fmaxf(mx, s[k]);
  float e[8], sum = 0.f;
  #pragma unroll
  for (int k = 0; k < 8; ++k) { e[k] = expf(s[k] - mx); sum += e[k]; }
  float inv = 1.0f / sum;

  float g0 = 0.f, g1 = 0.f, g2 = 0.f, g3 = 0.f;
  #pragma unroll
  for (int k = 0; k < 8; ++k) {
    float4 vv = *(const float4*)(vb + (size_t)nb[k]*NC + lane*4);
    float w = e[k] * inv;
    g0 = fmaf(w, vv.x, g0);
    g1 = fmaf(w, vv.y, g1);
    g2 = fmaf(w, vv.z, g2);
    g3 = fmaf(w, vv.w, g3);
  }
  uint32_t p0 = ((uint32_t)f2bf(g1) << 16) | f2bf(g0);
  uint32_t p1 = ((uint32_t)f2bf(g3) << 16) | f2bf(g2);
  *(uint2*)(g + (size_t)P*NC + lane*4) = make_uint2(p0, p1);
}

// ---------------- zero-fill ref halves of output (runs LAST) ----------------
__global__ void k_zero(float4* __restrict__ o) {
  int i = blockIdx.x * 256 + threadIdx.x;  // 0 .. 2097151
  int b = i >> 20;                         // region 0 or 1
  int r = i & 1048575;                     // 1M float4 per 16MB region
  o[(size_t)b * 2097152 + r] = make_float4(0.f, 0.f, 0.f, 0.f);
}

// ---------------- final GEMM: g[16384,256]bf16 @ A^T + bbig -> f32 ----------
__global__ __launch_bounds__(256) void k_gemm(const uint16_t* __restrict__ g,
    const uint16_t* __restrict__ Aw, const float* __restrict__ bbig,
    float* __restrict__ outp) {
  // LDS stride 136 (272B): 16B-aligned rows, 4-bank shift/row => conflict-free
  __shared__ __align__(16) uint16_t sA[64 * 136];
  __shared__ __align__(16) uint16_t sB[64 * 136];
  int t = threadIdx.x;
  int lane = t & 63, wave = t >> 6;
  int wm = (wave >> 1) * 32, wn = (wave & 1) * 32;
  int q = lane >> 4, rr = lane & 15;
  int bm = blockIdx.x;   // 0..255 (M tiles of 64)
  int bn = blockIdx.y;   // 0..7   (N tiles of 64)
  f32x4 zero = {0.f, 0.f, 0.f, 0.f};
  f32x4 acc[2][2] = {{zero, zero}, {zero, zero}};

  for (int ph = 0; ph < 2; ++ph) {      // K = 256 in two 128 phases
    #pragma unroll
    for (int i = 0; i < 4; ++i) {
      int cc  = t + i * 256;            // 0..1023 chunks of 8 bf16
      int row = cc >> 4;                // 16 chunks per row
      int col = (cc & 15) << 3;
      uint4 da = *(const uint4*)(g  + ((size_t)(bm*64 + row))*NC + ph*128 + col);
      *(uint4*)(&sA[row*136 + col]) = da;
      uint4 db = *(const uint4*)(Aw + ((size_t)(bn*64 + row))*NC + ph*128 + col);
      *(uint4*)(&sB[row*136 + col]) = db;
    }
    __syncthreads();
    #pragma unroll
    for (int kk = 0; kk < 4; ++kk) {
      int ko = kk*32 + q*8;
      bf16x8 a0 = *(const bf16x8*)(&sA[(wm      + rr)*136 + ko]);
      bf16x8 a1 = *(const bf16x8*)(&sA[(wm + 16 + rr)*136 + ko]);
      bf16x8 b0 = *(const bf16x8*)(&sB[(wn      + rr)*136 + ko]);
      bf16x8 b1 = *(const bf16x8*)(&sB[(wn + 16 + rr)*136 + ko]);
      acc[0][0] = __builtin_amdgcn_mfma_f32_16x16x32_bf16(a0, b0, acc[0][0], 0, 0, 0);
      acc[0][1] = __builtin_amdgcn_mfma_f32_16x16x32_bf16(a0, b1, acc[0][1], 0, 0, 0);
      acc[1][0] = __builtin_amdgcn_mfma_f32_16x16x32_bf16(a1, b0, acc[1][0], 0, 0, 0);
      acc[1][1] = __builtin_amdgcn_mfma_f32_16x16x32_bf16(a1, b1, acc[1][1], 0, 0, 0);
    }
    __syncthreads();
  }
  #pragma unroll
  for (int j = 0; j < 2; ++j) {
    int col = bn*64 + wn + j*16 + rr;
    float bias = bbig[col];
    #pragma unroll
    for (int i = 0; i < 2; ++i) {
      #pragma unroll
      for (int r = 0; r < 4; ++r) {
        int row = bm*64 + wm + i*16 + q*4 + r;   // C/D: col=lane&15, row=(lane>>4)*4+reg
        float v = acc[i][j][r] + bias;
        int bb = row >> 13, p = row & 8191;
        outp[((size_t)(bb*16384 + 8192 + p))*512 + col] = v;
      }
    }
  }
}

extern "C" void kernel_launch(void* const* d_in, const int* in_sizes, int n_in,
                              void* d_out, int out_size, void* d_ws, size_t ws_size,
                              hipStream_t stream) {
  const float* xyz_ref  = (const float*)d_in[0];
  const float* xyz_pred = (const float*)d_in[1];
  const float* feat_k   = (const float*)d_in[2];
  const float* feat_q   = (const float*)d_in[3];
  const float* feat_v   = (const float*)d_in[4];
  const float* Wv       = (const float*)d_in[5];
  const float* bv       = (const float*)d_in[6];
  const float* Wo       = (const float*)d_in[7];
  const float* bo       = (const float*)d_in[8];
  const float* Wout     = (const float*)d_in[9];
  float* outp = (float*)d_out;

  // ALL scratch inside d_out's dead ref-half regions (f32 output, 64MB):
  char* ob = (char*)d_out;
  uint16_t* g    = (uint16_t*)ob;                    // [0, 8M)    bf16 16384x256
  float4*   ref4 = (float4*)(ob + 8388608);          // [8M, 8.25M)
  int*      idx  = (int*)(ob + 8650752);             // [8.25M, 8.75M)
  uint16_t* Aw   = (uint16_t*)(ob + 9175040);        // [8.75M, 9M)
  float*    bbig = (float*)(ob + 9437184);           // [9M, +2K)
  uint16_t* part = (uint16_t*)(ob + 33554432);       // [32M, 40M)  8 MB u16

  k_prep   <<<64,   256, 0, stream>>>(xyz_ref, ref4);
  k_knn    <<<2048, 256, 0, stream>>>(xyz_pred, ref4, part);
  k_merge  <<<64,   256, 0, stream>>>(part, xyz_pred, ref4, idx);
  k_combine<<<64,   256, 0, stream>>>(Wv, bv, Wo, bo, Wout, Aw, bbig);
  k_attn   <<<4096, 256, 0, stream>>>(feat_q, feat_k, feat_v, idx, g);
  k_gemm   <<<dim3(256, 8), 256, 0, stream>>>(g, Aw, bbig, outp);
  k_zero   <<<8192, 256, 0, stream>>>((float4*)outp);
}